// Round 9
// baseline (113.417 us; speedup 1.0000x reference)
//
#include <hip/hip_runtime.h>
#include <stdint.h>

#define B_ 2
#define N_ 4096
#define C_ 8
#define MAXDET 100
#define SCORE_THR 0.01f
#define NMS_THR 0.5f
#define NEGV -1e30f

typedef unsigned long long u64;

// ---------- helpers ----------
__device__ __forceinline__ unsigned mono_key(float f) {
    unsigned u = __float_as_uint(f);
    return (u & 0x80000000u) ? ~u : (u | 0x80000000u);
}
__device__ __forceinline__ float mono_dec(unsigned m) {
    return (m & 0x80000000u) ? __uint_as_float(m ^ 0x80000000u)
                             : __uint_as_float(~m);
}
// exact predicate: RN32(inter/uni) > 0.5  (uni > 0)
__device__ __forceinline__ bool iou_gt_half(float inter, float uni) {
    return (inter + inter - uni) > uni * 0x1p-25f;
}
// wave-synchronous LDS fence (single-wave producer/consumer, no s_barrier)
__device__ __forceinline__ void wave_fence() {
    asm volatile("s_waitcnt lgkmcnt(0)" ::: "memory");
}
// compare-exchange: d=true keeps max at `a` (descending at lower index)
__device__ __forceinline__ void ce(u64 &a, u64 &b, bool d) {
    if ((a < b) == d) { u64 t = a; a = b; b = t; }
}

// ---------- kernel 1: per-(b,class) full 4096 sort (8 elems/thread,
// COMPACT rolled loops) + NMS mask + greedy scan -> cand list. -------------
__global__ __launch_bounds__(512) void sortnms_kernel(
    const float* __restrict__ cls,
    const float* __restrict__ boxes,
    u64* __restrict__ cand)   // (B*C, 128)
{
    __shared__ u64 m[4096];          // fully sorted array (desc)
    __shared__ float4 sb192[192];
    __shared__ float  sa192[192];
    __shared__ u64 cm[576];          // 192 rows x 3 words
    __shared__ float4 sbx[64];       // fallback only
    __shared__ u64 shJ[64];          // fallback only
    __shared__ int s_fin;

    const int bc = blockIdx.x;
    const int b = bc >> 3, cls_id = bc & 7;
    const int tid = threadIdx.x;
    const int lane = tid & 63;
    const int wave = tid >> 6;
    const float4* boxes4 = (const float4*)boxes;

    // ---- load 8 scores/thread, build keys (element e = tid*8 + j) ----
    u64 k[8];
    #pragma unroll
    for (int j = 0; j < 8; j++) {
        int i = tid * 8 + j;
        float s = cls[((size_t)b * N_ + i) * C_ + cls_id];
        float f = (s > SCORE_THR) ? s : NEGV;
        k[j] = ((u64)mono_key(f) << 32) | (unsigned)(~i);
    }

    // ---- bitonic sort, desc. dir d(e,size) = ((e & size) == 0).
    // prelude sizes 2,4 (within-thread, static d per element): ----
    ce(k[0], k[1], true ); ce(k[2], k[3], false);
    ce(k[4], k[5], true ); ce(k[6], k[7], false);
    ce(k[0], k[2], true ); ce(k[1], k[3], true );
    ce(k[4], k[6], false); ce(k[5], k[7], false);
    ce(k[0], k[1], true ); ce(k[2], k[3], true );
    ce(k[4], k[5], false); ce(k[6], k[7], false);

    // ---- main loop sizes 8..4096. For size>=8, d is uniform across the
    // thread's 8 elements: d = ((tid & (size>>3)) == 0). Strides >=512 via
    // LDS; 256..8 via shfl (runtime lane mask); 4,2,1 static in-thread. ----
    for (int size = 8; size <= 4096; size <<= 1) {
        const bool dthr = ((tid & (size >> 3)) == 0);
        int stride = size >> 1;
        if (stride >= 512) {
            #pragma unroll
            for (int j = 0; j < 8; j++) m[tid * 8 + j] = k[j];
            __syncthreads();
            for (; stride >= 512; stride >>= 1) {
                for (int tt = tid; tt < 2048; tt += 512) {
                    int pos = 2 * tt - (tt & (stride - 1));
                    int par = pos + stride;
                    bool d = ((pos & size) == 0);
                    u64 a = m[pos], bb = m[par];
                    if ((a < bb) == d) { m[pos] = bb; m[par] = a; }
                }
                __syncthreads();
            }
            #pragma unroll
            for (int j = 0; j < 8; j++) k[j] = m[tid * 8 + j];
        }
        for (; stride >= 8; stride >>= 1) {
            const int ls = stride >> 3;
            const bool takeMax = (dthr == ((tid & ls) == 0));
            #pragma unroll
            for (int j = 0; j < 8; j++) {
                u64 p = __shfl_xor(k[j], ls, 64);
                k[j] = takeMax ? (k[j] > p ? k[j] : p)
                               : (k[j] < p ? k[j] : p);
            }
        }
        ce(k[0], k[4], dthr); ce(k[1], k[5], dthr);
        ce(k[2], k[6], dthr); ce(k[3], k[7], dthr);
        ce(k[0], k[2], dthr); ce(k[1], k[3], dthr);
        ce(k[4], k[6], dthr); ce(k[5], k[7], dthr);
        ce(k[0], k[1], dthr); ce(k[2], k[3], dthr);
        ce(k[4], k[5], dthr); ce(k[6], k[7], dthr);
    }
    #pragma unroll
    for (int j = 0; j < 8; j++) m[tid * 8 + j] = k[j];   // sorted desc
    __syncthreads();

    // ---- gather top-192 boxes into LDS ----
    if (tid < 192) {
        int orig = (int)(~(unsigned)m[tid]);
        float4 bx = boxes4[(size_t)b * N_ + orig];
        sb192[tid] = bx;
        sa192[tid] = (bx.z - bx.x) * (bx.w - bx.y);
    }
    __syncthreads();

    // ---- cmask: 192 rows x 3 words ----
    for (int qq = tid; qq < 576; qq += 512) {
        int r = qq / 3, w = qq - 3 * r;
        int chunk = r >> 6;
        u64 bits = 0ull;
        if (w >= chunk) {
            float4 bi = sb192[r];
            float aarea = sa192[r];
            #pragma unroll 8
            for (int t = 0; t < 64; t++) {
                float4 bj = sb192[w * 64 + t];
                float barea = sa192[w * 64 + t];
                float ix1 = fmaxf(bi.x, bj.x);
                float iy1 = fmaxf(bi.y, bj.y);
                float ix2 = fminf(bi.z, bj.z);
                float iy2 = fminf(bi.w, bj.w);
                float inter = fmaxf(ix2 - ix1, 0.0f) * fmaxf(iy2 - iy1, 0.0f);
                float uni = fmaxf(aarea + barea - inter, 1e-9f);
                if (iou_gt_half(inter, uni)) bits |= (1ull << t);
            }
            if (w == chunk) bits &= ~((2ull << (r & 63)) - 1ull);
        }
        cm[qq] = bits;
    }
    __syncthreads();

    // ---- fast greedy scan, wave 0 only ----
    if (wave == 0) {
        u64 remv = 0ull;
        int cc = 0;
        bool fin = false;
        for (int c = 0; c < 3; c++) {
            int p = c * 64 + lane;
            u64 key = m[p];
            float sc = mono_dec((unsigned)(key >> 32));
            u64 validb = __ballot(sc > -1e29f);
            if (validb == 0ull) { fin = true; break; }

            u64 curw = __shfl(remv, c, 64);
            u64 kept = 0ull;
            for (int t = 0; t < 64; t++) {
                u64 iv = cm[(c * 64 + t) * 3 + c];
                u64 bit = 1ull << t;
                if (!(curw & bit) && (validb & bit)) { kept |= bit; curw |= iv; }
            }

            if ((kept >> lane) & 1ull) {
                int rank = cc + __popcll(kept & ((1ull << lane) - 1ull));
                if (rank < 128) {
                    int orig = (int)(~(unsigned)key);
                    unsigned flat = (unsigned)(cls_id * N_ + orig);
                    cand[bc * 128 + rank] =
                        ((u64)mono_key(sc) << 32) | (unsigned)(~flat);
                }
            }
            cc += __popcll(kept);
            if (cc >= 128) { fin = true; break; }

            if (lane < 3) {
                u64 acc = 0ull;
                for (int t = 0; t < 64; t++)
                    if ((kept >> t) & 1ull) acc |= cm[(c * 64 + t) * 3 + lane];
                remv |= acc;
            }
        }
        if (fin) {
            int filled = cc < 128 ? cc : 128;
            for (int s = lane; s < 128; s += 64)
                if (s >= filled) cand[bc * 128 + s] = 0ull;
        }
        if (lane == 0) s_fin = fin ? 1 : 0;
    }
    __syncthreads();
    if (s_fin) return;

    // ========== gated fallback (never on bench data): m already fully
    // sorted — wave-0 on-the-fly NMS over all 4096. =========================
    if (wave != 0) return;
    {
        u64 remv = 0ull;
        int cc = 0;
        for (int c = 0; c < 64; c++) {
            int p = c * 64 + lane;
            u64 key = m[p];
            float sc = mono_dec((unsigned)(key >> 32));
            u64 validb = __ballot(sc > -1e29f);
            if (validb == 0ull) break;

            int orig = (int)(~(unsigned)key);
            float4 bl = boxes4[(size_t)b * N_ + orig];
            sbx[lane] = bl;
            wave_fence();
            float al = (bl.z - bl.x) * (bl.w - bl.y);

            u64 intra = 0ull;
            for (int t = 0; t < 64; t++) {
                float4 bj = sbx[t];
                float ab = (bj.z - bj.x) * (bj.w - bj.y);
                float ix1 = fmaxf(bl.x, bj.x);
                float iy1 = fmaxf(bl.y, bj.y);
                float ix2 = fminf(bl.z, bj.z);
                float iy2 = fminf(bl.w, bj.w);
                float inter = fmaxf(ix2 - ix1, 0.0f) * fmaxf(iy2 - iy1, 0.0f);
                float uni = fmaxf(al + ab - inter, 1e-9f);
                if (t > lane && iou_gt_half(inter, uni)) intra |= (1ull << t);
            }
            shJ[lane] = intra;
            wave_fence();

            u64 curw = __shfl(remv, c, 64);
            u64 kept = 0ull;
            for (int t = 0; t < 64; t++) {
                u64 iv = shJ[t];
                u64 bit = 1ull << t;
                if (!(curw & bit) && (validb & bit)) { kept |= bit; curw |= iv; }
            }

            if ((kept >> lane) & 1ull) {
                int rank = cc + __popcll(kept & ((1ull << lane) - 1ull));
                if (rank < 128) {
                    unsigned flat = (unsigned)(cls_id * N_ + orig);
                    cand[bc * 128 + rank] =
                        ((u64)mono_key(sc) << 32) | (unsigned)(~flat);
                }
            }
            cc += __popcll(kept);
            if (cc >= 128) break;

            if (lane > c) {
                u64 accw = 0ull;
                for (int u = 0; u < 64; u++) {
                    int pj = lane * 64 + u;
                    int oj = (int)(~(unsigned)m[pj]);
                    float4 bj = boxes4[(size_t)b * N_ + oj];
                    float ab = (bj.z - bj.x) * (bj.w - bj.y);
                    bool sup = false;
                    for (int tt = 0; tt < 64; tt++) {
                        if (!((kept >> tt) & 1ull)) continue;
                        float4 br = sbx[tt];
                        float ar = (br.z - br.x) * (br.w - br.y);
                        float ix1 = fmaxf(br.x, bj.x);
                        float iy1 = fmaxf(br.y, bj.y);
                        float ix2 = fminf(br.z, bj.z);
                        float iy2 = fminf(br.w, bj.w);
                        float inter = fmaxf(ix2 - ix1, 0.0f) * fmaxf(iy2 - iy1, 0.0f);
                        float uni = fmaxf(ar + ab - inter, 1e-9f);
                        if (iou_gt_half(inter, uni)) { sup = true; break; }
                    }
                    if (sup) accw |= (1ull << u);
                }
                remv |= accw;
            }
            wave_fence();
        }
        int filled = cc < 128 ? cc : 128;
        for (int s = lane; s < 128; s += 64)
            if (s >= filled) cand[bc * 128 + s] = 0ull;
    }
}

// ---------- kernel 2: merge 8 sorted 128-lists -> top-100, write outputs --
__global__ __launch_bounds__(1024) void merge_kernel(
    const u64* __restrict__ cand,
    const float* __restrict__ boxes,
    const float* __restrict__ rot,
    const float* __restrict__ trans,
    float* __restrict__ out)
{
    __shared__ u64 sk[1024];
    const int b = blockIdx.x;
    const int tid = threadIdx.x;
    const int c = tid >> 7, s = tid & 127;

    // per-class lists sorted desc; load odd classes reversed (asc)
    int src = (c & 1) ? (c * 128 + (127 - s)) : tid;
    sk[tid] = cand[(size_t)b * 1024 + src];

    for (int size = 256; size <= 1024; size <<= 1) {
        for (int stride = size >> 1; stride > 0; stride >>= 1) {
            __syncthreads();
            int partner = tid ^ stride;
            if (partner > tid) {
                bool desc = ((tid & size) == 0);
                u64 a = sk[tid], bb = sk[partner];
                if ((a < bb) == desc) { sk[tid] = bb; sk[partner] = a; }
            }
        }
    }
    __syncthreads();

    if (tid < MAXDET) {
        u64 key = sk[tid];
        float score = mono_dec((unsigned)(key >> 32));
        bool ok = score > (NEGV * 0.5f);
        unsigned flat = (~(unsigned)key) & 32767u;
        int cc = flat >> 12;
        int n = flat & (N_ - 1);

        float* obox = out;                   // 800
        float* oscr = out + 800;             // 200
        float* olab = out + 1000;            // 200
        float* orot = out + 1200;            // 600
        float* otrn = out + 1800;            // 600

        #pragma unroll
        for (int d = 0; d < 4; d++)
            obox[b * 400 + tid * 4 + d] =
                ok ? boxes[((size_t)b * N_ + n) * 4 + d] : -1.0f;
        oscr[b * MAXDET + tid] = ok ? score : -1.0f;
        olab[b * MAXDET + tid] = ok ? (float)cc : -1.0f;
        #pragma unroll
        for (int d = 0; d < 3; d++) {
            orot[b * 300 + tid * 3 + d] =
                ok ? rot[((size_t)b * N_ + n) * 3 + d] : -1.0f;
            otrn[b * 300 + tid * 3 + d] =
                ok ? trans[((size_t)b * N_ + n) * 3 + d] : -1.0f;
        }
    }
}

extern "C" void kernel_launch(void* const* d_in, const int* in_sizes, int n_in,
                              void* d_out, int out_size, void* d_ws, size_t ws_size,
                              hipStream_t stream) {
    const float* boxes = (const float*)d_in[0];
    const float* cls   = (const float*)d_in[1];
    const float* rot   = (const float*)d_in[2];
    const float* trans = (const float*)d_in[3];
    float* out = (float*)d_out;

    u64* cand = (u64*)d_ws;   // 16 KB

    sortnms_kernel<<<B_ * C_, 512, 0, stream>>>(cls, boxes, cand);
    merge_kernel<<<B_, 1024, 0, stream>>>(cand, boxes, rot, trans, out);
}

// Round 12
// 96.393 us; speedup vs baseline: 1.1766x; 1.1766x over previous
//
#include <hip/hip_runtime.h>
#include <stdint.h>

#define B_ 2
#define N_ 4096
#define C_ 8
#define MAXDET 100
#define SCORE_THR 0.01f
#define NMS_THR 0.5f
#define NEGV -1e30f

typedef unsigned long long u64;

// ---------- helpers ----------
__device__ __forceinline__ unsigned mono_key(float f) {
    unsigned u = __float_as_uint(f);
    return (u & 0x80000000u) ? ~u : (u | 0x80000000u);
}
__device__ __forceinline__ float mono_dec(unsigned m) {
    return (m & 0x80000000u) ? __uint_as_float(m ^ 0x80000000u)
                             : __uint_as_float(~m);
}
// exact predicate: RN32(inter/uni) > 0.5  (uni > 0)
__device__ __forceinline__ bool iou_gt_half(float inter, float uni) {
    return (inter + inter - uni) > uni * 0x1p-25f;
}
// wave-synchronous LDS fence (single-wave producer/consumer, no s_barrier)
__device__ __forceinline__ void wave_fence() {
    asm volatile("s_waitcnt lgkmcnt(0)" ::: "memory");
}

// ---------- register-resident bitonic helpers (layout: thread t holds
// elements 2t and 2t+1; element-stride s<=64 -> lane xor mask s/2<=32) ------
__device__ __forceinline__ void ce_shfl(u64 &e0, u64 &e1, int tid, int size,
                                        int stride, bool desc) {
    const int m = stride >> 1;
    bool d = (((2 * tid) & size) == 0) ? desc : !desc;   // true = descending
    bool lower = (tid & m) == 0;
    u64 p0 = __shfl_xor(e0, m, 64);
    u64 p1 = __shfl_xor(e1, m, 64);
    bool takeMax = (d == lower);
    e0 = takeMax ? (e0 > p0 ? e0 : p0) : (e0 < p0 ? e0 : p0);
    e1 = takeMax ? (e1 > p1 ? e1 : p1) : (e1 < p1 ? e1 : p1);
}
__device__ __forceinline__ void ce_intra(u64 &e0, u64 &e1, int tid, int size,
                                         bool desc) {
    bool d = (((2 * tid) & size) == 0) ? desc : !desc;
    if ((e0 < e1) == d) { u64 t = e0; e0 = e1; e1 = t; }
}

// ---------- 1) sort phase A: per-1024-chunk hybrid bitonic, alt dirs ------
__global__ __launch_bounds__(512) void sortA_kernel(
    const float* __restrict__ cls,
    u64* __restrict__ keys)   // (B*C, N)
{
    __shared__ u64 k[1024];
    const int q = blockIdx.x;        // quarter 0..3
    const int bc = blockIdx.y;
    const int b = bc >> 3, c = bc & 7;
    const int tid = threadIdx.x;
    const bool desc = ((q & 1) == 0);

    u64 e0, e1;
    {
        int i0 = q * 1024 + 2 * tid;
        float s0 = cls[((size_t)b * N_ + i0) * C_ + c];
        float s1 = cls[((size_t)b * N_ + i0 + 1) * C_ + c];
        float f0 = (s0 > SCORE_THR) ? s0 : NEGV;
        float f1 = (s1 > SCORE_THR) ? s1 : NEGV;
        e0 = ((u64)mono_key(f0) << 32) | (unsigned)(~i0);
        e1 = ((u64)mono_key(f1) << 32) | (unsigned)(~(i0 + 1));
    }

    // sizes 2..128: entirely in registers (strides <=64 -> lane mask <=32)
    #pragma unroll
    for (int size = 2; size <= 128; size <<= 1) {
        #pragma unroll
        for (int stride = size >> 1; stride >= 2; stride >>= 1)
            ce_shfl(e0, e1, tid, size, stride, desc);
        ce_intra(e0, e1, tid, size, desc);
    }
    // sizes 256..1024: strides >=128 via LDS, small strides in registers
    #pragma unroll
    for (int size = 256; size <= 1024; size <<= 1) {
        k[2 * tid] = e0; k[2 * tid + 1] = e1;
        __syncthreads();
        for (int stride = size >> 1; stride >= 128; stride >>= 1) {
            int pos = 2 * tid - (tid & (stride - 1));
            int par = pos + stride;
            bool d = ((pos & size) == 0) ? desc : !desc;
            u64 a = k[pos], bb = k[par];
            if ((a < bb) == d) { k[pos] = bb; k[par] = a; }
            __syncthreads();
        }
        e0 = k[2 * tid]; e1 = k[2 * tid + 1];
        #pragma unroll
        for (int stride = 64; stride >= 2; stride >>= 1)
            ce_shfl(e0, e1, tid, size, stride, desc);
        ce_intra(e0, e1, tid, size, desc);
    }

    ulonglong2 v; v.x = e0; v.y = e1;
    *(ulonglong2*)&keys[(size_t)bc * N_ + q * 1024 + 2 * tid] = v;
}

// ---------- 2) fused: top-1024 merge + mask + greedy scan (+gated fallback) -
__global__ __launch_bounds__(512) void fused_kernel(
    const u64* __restrict__ keys,
    const float* __restrict__ boxes,
    u64* __restrict__ cand)   // (B*C, 128)
{
    __shared__ u64 m[4096];          // fast: top-1024; fallback: all 4096
    __shared__ float4 sb192[192];
    __shared__ float  sa192[192];
    __shared__ u64 cm[576];          // 192 rows x 3 words
    __shared__ float4 sbx[64];       // fallback only
    __shared__ u64 shJ[64];          // fallback only
    __shared__ int s_fin;

    const int bc = blockIdx.x;
    const int b = bc >> 3, cls = bc & 7;
    const int tid = threadIdx.x;
    const int lane = tid & 63;
    const int wave = tid >> 6;
    const size_t kbase = (size_t)bc * N_;
    const float4* boxes4 = (const float4*)boxes;

    // ---- load 4 x top-256 (quarters sorted desc/asc/desc/asc) into regs ----
    u64 e0, e1;
    {
        int i = 2 * tid;                 // merged-array element index (pair)
        int qq = i >> 8;
        int off = qq * 1024 + ((qq & 1) ? 768 : 0) + (i & 255);
        ulonglong2 v = *(const ulonglong2*)&keys[kbase + off];
        e0 = v.x; e1 = v.y;
    }

    // ---- finish bitonic on 1024 (sizes 512,1024), hybrid reg/LDS ----
    #pragma unroll
    for (int size = 512; size <= 1024; size <<= 1) {
        m[2 * tid] = e0; m[2 * tid + 1] = e1;
        __syncthreads();
        for (int stride = size >> 1; stride >= 128; stride >>= 1) {
            int pos = 2 * tid - (tid & (stride - 1));
            int par = pos + stride;
            bool d = ((pos & size) == 0);
            u64 a = m[pos], bb = m[par];
            if ((a < bb) == d) { m[pos] = bb; m[par] = a; }
            __syncthreads();
        }
        e0 = m[2 * tid]; e1 = m[2 * tid + 1];
        #pragma unroll
        for (int stride = 64; stride >= 2; stride >>= 1)
            ce_shfl(e0, e1, tid, size, stride, true);
        ce_intra(e0, e1, tid, size, true);
    }
    m[2 * tid] = e0; m[2 * tid + 1] = e1;
    __syncthreads();

    // ---- gather top-192 boxes into LDS ----
    if (tid < 192) {
        int orig = (int)(~(unsigned)m[tid]);
        float4 bx = boxes4[(size_t)b * N_ + orig];
        sb192[tid] = bx;
        sa192[tid] = (bx.z - bx.x) * (bx.w - bx.y);
    }
    __syncthreads();

    // ---- cmask: 192 rows x 3 words; exactly <=1 IoU task per thread ----
    // real tasks (w >= chunk(r)=r>>6): (r,2) all 192; (r,1) r<128; (r,0) r<64
    // -> 384 IoU tasks on threads 0..383. Zero slots (w < chunk): (r,0) for
    // r in 64..191 (128) + (r,1) for r in 128..191 (64) = 192, zeroed by
    // threads 384..511 (1-2 stores each, no IoU work).
    {
        int s = tid, r = -1, w = 0;
        if (s < 192)      { r = s;       w = 2; }
        else if (s < 320) { r = s - 192; w = 1; }
        else if (s < 384) { r = s - 320; w = 0; }
        if (r >= 0) {
            float4 bi = sb192[r];
            float aarea = sa192[r];
            u64 bits = 0ull;
            #pragma unroll 8
            for (int t = 0; t < 64; t++) {
                float4 bj = sb192[w * 64 + t];
                float barea = sa192[w * 64 + t];
                float ix1 = fmaxf(bi.x, bj.x);
                float iy1 = fmaxf(bi.y, bj.y);
                float ix2 = fminf(bi.z, bj.z);
                float iy2 = fminf(bi.w, bj.w);
                float inter = fmaxf(ix2 - ix1, 0.0f) * fmaxf(iy2 - iy1, 0.0f);
                float uni = fmaxf(aarea + barea - inter, 1e-9f);
                if (iou_gt_half(inter, uni)) bits |= (1ull << t);
            }
            if (w == (r >> 6)) bits &= ~((2ull << (r & 63)) - 1ull);
            cm[r * 3 + w] = bits;
        } else {
            int z = s - 384;                    // 0..127
            cm[(64 + z) * 3 + 0] = 0ull;        // (64..191, 0): all 128
            if (z < 64)
                cm[(128 + z) * 3 + 1] = 0ull;   // (128..191, 1): all 64
        }
    }
    __syncthreads();

    // ---- fast greedy scan, wave 0 only, fully LDS-resident ----
    if (wave == 0) {
        u64 remv = 0ull;     // lane w owns removal word w (only 0..2 used)
        int cc = 0;
        bool fin = false;
        for (int c = 0; c < 3; c++) {
            int p = c * 64 + lane;
            u64 key = m[p];
            float sc = mono_dec((unsigned)(key >> 32));
            u64 validb = __ballot(sc > -1e29f);
            if (validb == 0ull) { fin = true; break; }

            // preload lane's diag word once; broadcast via shfl in the
            // serial chain (removes 64 dependent LDS reads per c-iter)
            u64 ivr = cm[(c * 64 + lane) * 3 + c];
            u64 curw = __shfl(remv, c, 64);
            u64 kept = 0ull;
            for (int t = 0; t < 64; t++) {
                u64 iv = __shfl(ivr, t, 64);
                u64 bit = 1ull << t;
                if (!(curw & bit) && (validb & bit)) { kept |= bit; curw |= iv; }
            }

            if ((kept >> lane) & 1ull) {
                int rank = cc + __popcll(kept & ((1ull << lane) - 1ull));
                if (rank < 128) {
                    int orig = (int)(~(unsigned)key);
                    unsigned flat = (unsigned)(cls * N_ + orig);
                    cand[bc * 128 + rank] =
                        ((u64)mono_key(sc) << 32) | (unsigned)(~flat);
                }
            }
            cc += __popcll(kept);
            if (cc >= 128) { fin = true; break; }

            if (lane < 3) {
                u64 acc = 0ull;
                for (int t = 0; t < 64; t++)
                    if ((kept >> t) & 1ull) acc |= cm[(c * 64 + t) * 3 + lane];
                remv |= acc;
            }
        }
        if (fin) {
            int filled = cc < 128 ? cc : 128;
            for (int s = lane; s < 128; s += 64)
                if (s >= filled) cand[bc * 128 + s] = 0ull;
        }
        if (lane == 0) s_fin = fin ? 1 : 0;
    }
    __syncthreads();
    if (s_fin) return;

    // ================= gated fallback (never on bench data) =================
    // finish the full 4096 sort in LDS, then wave-0 on-the-fly NMS.
    for (int i = tid; i < 4096; i += 512) m[i] = keys[kbase + i];
    __syncthreads();
    for (int size = 2048; size <= 4096; size <<= 1) {
        for (int stride = size >> 1; stride > 0; stride >>= 1) {
            for (int t = tid; t < 2048; t += 512) {
                int pos = 2 * t - (t & (stride - 1));
                int par = pos + stride;
                bool d = ((pos & size) == 0);
                u64 a = m[pos], bb = m[par];
                if ((a < bb) == d) { m[pos] = bb; m[par] = a; }
            }
            __syncthreads();
        }
    }
    if (wave != 0) return;

    {
        u64 remv = 0ull;
        int cc = 0;
        for (int c = 0; c < 64; c++) {
            int p = c * 64 + lane;
            u64 key = m[p];
            float sc = mono_dec((unsigned)(key >> 32));
            u64 validb = __ballot(sc > -1e29f);
            if (validb == 0ull) break;

            int orig = (int)(~(unsigned)key);
            float4 bl = boxes4[(size_t)b * N_ + orig];
            sbx[lane] = bl;
            wave_fence();
            float al = (bl.z - bl.x) * (bl.w - bl.y);

            u64 intra = 0ull;
            for (int t = 0; t < 64; t++) {
                float4 bj = sbx[t];
                float ab = (bj.z - bj.x) * (bj.w - bj.y);
                float ix1 = fmaxf(bl.x, bj.x);
                float iy1 = fmaxf(bl.y, bj.y);
                float ix2 = fminf(bl.z, bj.z);
                float iy2 = fminf(bl.w, bj.w);
                float inter = fmaxf(ix2 - ix1, 0.0f) * fmaxf(iy2 - iy1, 0.0f);
                float uni = fmaxf(al + ab - inter, 1e-9f);
                if (t > lane && iou_gt_half(inter, uni)) intra |= (1ull << t);
            }
            shJ[lane] = intra;
            wave_fence();

            u64 curw = __shfl(remv, c, 64);
            u64 kept = 0ull;
            for (int t = 0; t < 64; t++) {
                u64 iv = shJ[t];
                u64 bit = 1ull << t;
                if (!(curw & bit) && (validb & bit)) { kept |= bit; curw |= iv; }
            }

            if ((kept >> lane) & 1ull) {
                int rank = cc + __popcll(kept & ((1ull << lane) - 1ull));
                if (rank < 128) {
                    unsigned flat = (unsigned)(cls * N_ + orig);
                    cand[bc * 128 + rank] =
                        ((u64)mono_key(sc) << 32) | (unsigned)(~flat);
                }
            }
            cc += __popcll(kept);
            if (cc >= 128) break;

            if (lane > c) {
                u64 accw = 0ull;
                for (int u = 0; u < 64; u++) {
                    int pj = lane * 64 + u;
                    int oj = (int)(~(unsigned)m[pj]);
                    float4 bj = boxes4[(size_t)b * N_ + oj];
                    float ab = (bj.z - bj.x) * (bj.w - bj.y);
                    bool sup = false;
                    for (int tt = 0; tt < 64; tt++) {
                        if (!((kept >> tt) & 1ull)) continue;
                        float4 br = sbx[tt];
                        float ar = (br.z - br.x) * (br.w - br.y);
                        float ix1 = fmaxf(br.x, bj.x);
                        float iy1 = fmaxf(br.y, bj.y);
                        float ix2 = fminf(br.z, bj.z);
                        float iy2 = fminf(br.w, bj.w);
                        float inter = fmaxf(ix2 - ix1, 0.0f) * fmaxf(iy2 - iy1, 0.0f);
                        float uni = fmaxf(ar + ab - inter, 1e-9f);
                        if (iou_gt_half(inter, uni)) { sup = true; break; }
                    }
                    if (sup) accw |= (1ull << u);
                }
                remv |= accw;
            }
            wave_fence();
        }
        int filled = cc < 128 ? cc : 128;
        for (int s = lane; s < 128; s += 64)
            if (s >= filled) cand[bc * 128 + s] = 0ull;
    }
}

// ---------- 3) merge 8 sorted 128-lists -> top-100, write outputs ----------
__global__ __launch_bounds__(1024) void merge_kernel(
    const u64* __restrict__ cand,
    const float* __restrict__ boxes,
    const float* __restrict__ rot,
    const float* __restrict__ trans,
    float* __restrict__ out)
{
    __shared__ u64 sk[1024];
    const int b = blockIdx.x;
    const int tid = threadIdx.x;
    const int c = tid >> 7, s = tid & 127;

    // per-class lists sorted desc; load odd classes reversed (asc)
    int src = (c & 1) ? (c * 128 + (127 - s)) : tid;
    sk[tid] = cand[(size_t)b * 1024 + src];

    for (int size = 256; size <= 1024; size <<= 1) {
        for (int stride = size >> 1; stride > 0; stride >>= 1) {
            __syncthreads();
            int partner = tid ^ stride;
            if (partner > tid) {
                bool desc = ((tid & size) == 0);
                u64 a = sk[tid], bb = sk[partner];
                if ((a < bb) == desc) { sk[tid] = bb; sk[partner] = a; }
            }
        }
    }
    __syncthreads();

    if (tid < MAXDET) {
        u64 key = sk[tid];
        float score = mono_dec((unsigned)(key >> 32));
        bool ok = score > (NEGV * 0.5f);
        unsigned flat = (~(unsigned)key) & 32767u;
        int cc = flat >> 12;
        int n = flat & (N_ - 1);

        float* obox = out;                   // 800
        float* oscr = out + 800;             // 200
        float* olab = out + 1000;            // 200
        float* orot = out + 1200;            // 600
        float* otrn = out + 1800;            // 600

        #pragma unroll
        for (int d = 0; d < 4; d++)
            obox[b * 400 + tid * 4 + d] =
                ok ? boxes[((size_t)b * N_ + n) * 4 + d] : -1.0f;
        oscr[b * MAXDET + tid] = ok ? score : -1.0f;
        olab[b * MAXDET + tid] = ok ? (float)cc : -1.0f;
        #pragma unroll
        for (int d = 0; d < 3; d++) {
            orot[b * 300 + tid * 3 + d] =
                ok ? rot[((size_t)b * N_ + n) * 3 + d] : -1.0f;
            otrn[b * 300 + tid * 3 + d] =
                ok ? trans[((size_t)b * N_ + n) * 3 + d] : -1.0f;
        }
    }
}

extern "C" void kernel_launch(void* const* d_in, const int* in_sizes, int n_in,
                              void* d_out, int out_size, void* d_ws, size_t ws_size,
                              hipStream_t stream) {
    const float* boxes = (const float*)d_in[0];
    const float* cls   = (const float*)d_in[1];
    const float* rot   = (const float*)d_in[2];
    const float* trans = (const float*)d_in[3];
    float* out = (float*)d_out;

    char* w = (char*)d_ws;
    u64* keys = (u64*)w;   w += (size_t)B_ * C_ * N_ * sizeof(u64);   // 512 KB
    u64* cand = (u64*)w;   w += (size_t)B_ * C_ * 128 * sizeof(u64);  // 16 KB

    sortA_kernel<<<dim3(4, B_ * C_), 512, 0, stream>>>(cls, keys);
    fused_kernel<<<B_ * C_, 512, 0, stream>>>(keys, boxes, cand);
    merge_kernel<<<B_, 1024, 0, stream>>>(cand, boxes, rot, trans, out);
}